// Round 10
// baseline (394.480 us; speedup 1.0000x reference)
//
#include <hip/hip_runtime.h>
#include <hip/hip_bf16.h>
#include <hip/hip_fp16.h>

// GraphSAGE 3-layer + pool + linear.
// R10: gemm register-budget fix (R9 likely spilled: acc96+tmp64+Af48+B64>256).
// Staging now 2 batches of 8 uint4 (32 regs), B-frags consumed hi-phase then
// lo-phase (32 live), all global loads for source p issued BEFORE the barrier
// closing source p-1. agg: x8-unrolled gathers (8 outstanding 256B/node).
// Numerics: fp16 A + exact split-fp16 W (hi+lo), C = A*Whi + A*Wlo.

#define FH 128
#define OUTD 256
#define SCHUNK 2048

typedef unsigned int u32;
typedef unsigned short u16;
typedef __attribute__((ext_vector_type(8))) _Float16 f16frag;
typedef __attribute__((ext_vector_type(4))) float f4frag;

// ---------------------------------------------------------------- histogram
__global__ void hist_kernel(const int* __restrict__ dst, int* __restrict__ cnt, int E) {
    int e = blockIdx.x * 256 + threadIdx.x;
    if (e < E) atomicAdd(&cnt[dst[e]], 1);
}

// ---------------------------------------------- scan pass A: per-block sums
__global__ void scanA_kernel(const int* __restrict__ cnt, int* __restrict__ bsum, int n) {
    __shared__ int ws[4];
    int b = blockIdx.x, t = threadIdx.x;
    int base = b * SCHUNK + t * 8;
    int s = 0;
    #pragma unroll
    for (int k = 0; k < 8; ++k) {
        int i = base + k;
        s += (i < n) ? cnt[i] : 0;
    }
    #pragma unroll
    for (int off = 32; off >= 1; off >>= 1) s += __shfl_xor(s, off, 64);
    int w = t >> 6, lane = t & 63;
    if (lane == 0) ws[w] = s;
    __syncthreads();
    if (t == 0) bsum[b] = ws[0] + ws[1] + ws[2] + ws[3];
}

// ------------------------------- scan pass B: scan block sums (1 wave)
__global__ void scanB_kernel(const int* __restrict__ bsum, int* __restrict__ boff,
                             int* __restrict__ rp, int B, int n) {
    int t = threadIdx.x;  // 64 threads
    int v = (t < B) ? bsum[t] : 0;
    int x = v;
    #pragma unroll
    for (int off = 1; off < 64; off <<= 1) {
        int y = __shfl_up(x, off, 64);
        if (t >= off) x += y;
    }
    if (t < B) boff[t] = x - v;
    if (t == 63) rp[n] = x;
}

// --------------------------- scan pass C: full exclusive scan + emit rp/dinv
__global__ void scanC_kernel(const int* __restrict__ cnt, const int* __restrict__ boff,
                             int* __restrict__ rp, float* __restrict__ dinv, int n) {
    __shared__ int ws[4];
    int b = blockIdx.x, t = threadIdx.x;
    int base = b * SCHUNK + t * 8;
    int v[8];
    int ts = 0;
    #pragma unroll
    for (int k = 0; k < 8; ++k) {
        int i = base + k;
        v[k] = (i < n) ? cnt[i] : 0;
        ts += v[k];
    }
    int w = t >> 6, lane = t & 63;
    int x = ts;
    #pragma unroll
    for (int off = 1; off < 64; off <<= 1) {
        int y = __shfl_up(x, off, 64);
        if (lane >= off) x += y;
    }
    if (lane == 63) ws[w] = x;
    __syncthreads();
    int woff = 0;
    #pragma unroll
    for (int q = 0; q < 4; ++q) woff += (q < w) ? ws[q] : 0;
    int run = boff[b] + woff + (x - ts);
    #pragma unroll
    for (int k = 0; k < 8; ++k) {
        int i = base + k;
        if (i < n) {
            rp[i] = run;
            dinv[i] = 1.0f / (float)max(v[k], 1);
        }
        run += v[k];
    }
}

// --------------------------------------------------------- CSR edge scatter
__global__ void scatter_kernel(const int* __restrict__ src, const int* __restrict__ dst,
                               const int* __restrict__ rp, int* __restrict__ cursor,
                               int* __restrict__ esrc, int E) {
    int e = blockIdx.x * 256 + threadIdx.x;
    if (e < E) {
        int d = dst[e];
        int pos = rp[d] + atomicAdd(&cursor[d], 1);
        esrc[pos] = src[e];
    }
}

// ------------------------------------------------------- graph range bounds
__global__ void graph_bounds_kernel(const int* __restrict__ batch, int* __restrict__ gstart,
                                    int n, int g) {
    int i = blockIdx.x * 256 + threadIdx.x;
    if (i >= n) return;
    int b = batch[i];
    int pb = (i == 0) ? -1 : batch[i - 1];
    for (int q = pb + 1; q <= b; ++q) gstart[q] = i;
    if (i == n - 1) {
        for (int q = b + 1; q <= g; ++q) gstart[q] = n;
    }
}

// ---------------------------------------------------- prep: x -> fp16 mirror
__global__ void prep_x(const float* __restrict__ x, u16* __restrict__ x16, int n4) {
    int id = blockIdx.x * 256 + threadIdx.x;
    if (id >= n4) return;
    float4 v = *(const float4*)(x + (size_t)id * 4);
    __half h0 = __float2half(v.x), h1 = __float2half(v.y);
    __half h2 = __float2half(v.z), h3 = __float2half(v.w);
    ushort4 s;
    s.x = *(u16*)&h0; s.y = *(u16*)&h1; s.z = *(u16*)&h2; s.w = *(u16*)&h3;
    *(ushort4*)(x16 + (size_t)id * 4) = s;
}

// ------------------- prep: weights -> fp16 hi/lo B fragments (MFMA order)
// Per array: Bf[(ks*8 + ot)*64 + lane], lane l holds
// W[out=ot*16+(l&15)][k = (ks&3)*32 + (l>>4)*8 + i], i=0..7.
// ks 0-3: hi = f16(W); ks 4-7: lo = f16(W - hi).
__global__ void prep_w(const float* __restrict__ W0, const float* __restrict__ W1,
                       const float* __restrict__ W2, const float* __restrict__ W3,
                       const float* __restrict__ W4, const float* __restrict__ W5,
                       uint4* __restrict__ Bf) {
    const float* Ws[6] = {W0, W1, W2, W3, W4, W5};
    int ks = blockIdx.x;      // 0..7
    int arr = blockIdx.y;     // 0..5
    int l = threadIdx.x;      // 0..63
    const float* W = Ws[arr];
    bool use_lo = (ks >= 4);
    int kb = (ks & 3) * 32 + (l >> 4) * 8;
    uint4* out = Bf + (size_t)arr * 4096;
    #pragma unroll
    for (int ot = 0; ot < 8; ++ot) {
        int o = ot * 16 + (l & 15);
        u32 h[8];
        #pragma unroll
        for (int i = 0; i < 8; ++i) {
            float v = W[o * 128 + kb + i];
            __half hi = __float2half(v);
            if (use_lo) {
                float rem = v - __half2float(hi);
                __half lo = __float2half(rem);
                h[i] = *(u16*)&lo;
            } else {
                h[i] = *(u16*)&hi;
            }
        }
        uint4 u;
        u.x = h[0] | (h[1] << 16);
        u.y = h[2] | (h[3] << 16);
        u.z = h[4] | (h[5] << 16);
        u.w = h[6] | (h[7] << 16);
        out[(ks * 8 + ot) * 64 + l] = u;
    }
}

// --------------------------------------------------- mean aggregation (CSR)
// 16 lanes per node; lane covers 8 fp16 features (uint4 = 16B); x8 edge unroll
// -> 8 independent 256B gathers in flight per node group.
__device__ inline void add8(float* a, uint4 u) {
    float2 f0 = __half22float2(*(__half2*)&u.x);
    float2 f1 = __half22float2(*(__half2*)&u.y);
    float2 f2 = __half22float2(*(__half2*)&u.z);
    float2 f3 = __half22float2(*(__half2*)&u.w);
    a[0] += f0.x; a[1] += f0.y; a[2] += f1.x; a[3] += f1.y;
    a[4] += f2.x; a[5] += f2.y; a[6] += f3.x; a[7] += f3.y;
}

__global__ void agg_kernel(const u16* __restrict__ h16,
                           const int* __restrict__ rp, const int* __restrict__ esrc,
                           const float* __restrict__ dinv,
                           u16* __restrict__ agg16, int n_nodes) {
    int node = blockIdx.x * 16 + (threadIdx.x >> 4);
    if (node >= n_nodes) return;
    int lane = threadIdx.x & 15;
    int f = lane * 8;
    int s0 = rp[node], s1 = rp[node + 1];
    float a0[8] = {0, 0, 0, 0, 0, 0, 0, 0};
    float a1[8] = {0, 0, 0, 0, 0, 0, 0, 0};
    float a2[8] = {0, 0, 0, 0, 0, 0, 0, 0};
    float a3[8] = {0, 0, 0, 0, 0, 0, 0, 0};
    int j = s0;
    for (; j + 8 <= s1; j += 8) {
        int i0 = esrc[j],     i1 = esrc[j + 1], i2 = esrc[j + 2], i3 = esrc[j + 3];
        int i4 = esrc[j + 4], i5 = esrc[j + 5], i6 = esrc[j + 6], i7 = esrc[j + 7];
        uint4 u0 = *(const uint4*)(h16 + (size_t)i0 * FH + f);
        uint4 u1 = *(const uint4*)(h16 + (size_t)i1 * FH + f);
        uint4 u2 = *(const uint4*)(h16 + (size_t)i2 * FH + f);
        uint4 u3 = *(const uint4*)(h16 + (size_t)i3 * FH + f);
        uint4 u4 = *(const uint4*)(h16 + (size_t)i4 * FH + f);
        uint4 u5 = *(const uint4*)(h16 + (size_t)i5 * FH + f);
        uint4 u6 = *(const uint4*)(h16 + (size_t)i6 * FH + f);
        uint4 u7 = *(const uint4*)(h16 + (size_t)i7 * FH + f);
        add8(a0, u0); add8(a1, u1); add8(a2, u2); add8(a3, u3);
        add8(a0, u4); add8(a1, u5); add8(a2, u6); add8(a3, u7);
    }
    if (j + 4 <= s1) {
        int i0 = esrc[j], i1 = esrc[j + 1], i2 = esrc[j + 2], i3 = esrc[j + 3];
        uint4 u0 = *(const uint4*)(h16 + (size_t)i0 * FH + f);
        uint4 u1 = *(const uint4*)(h16 + (size_t)i1 * FH + f);
        uint4 u2 = *(const uint4*)(h16 + (size_t)i2 * FH + f);
        uint4 u3 = *(const uint4*)(h16 + (size_t)i3 * FH + f);
        add8(a0, u0); add8(a1, u1); add8(a2, u2); add8(a3, u3);
        j += 4;
    }
    for (; j < s1; ++j) {
        uint4 u0 = *(const uint4*)(h16 + (size_t)esrc[j] * FH + f);
        add8(a0, u0);
    }
    float di = dinv[node];
    u32 oh[8];
    #pragma unroll
    for (int i = 0; i < 8; ++i) {
        __half hv = __float2half((a0[i] + a1[i] + a2[i] + a3[i]) * di);
        oh[i] = *(u16*)&hv;
    }
    uint4 w;
    w.x = oh[0] | (oh[1] << 16);
    w.y = oh[2] | (oh[3] << 16);
    w.z = oh[4] | (oh[5] << 16);
    w.w = oh[6] | (oh[7] << 16);
    *(uint4*)(agg16 + (size_t)node * FH + f) = w;
}

// ----------------------------------------------------------- MFMA SAGE GEMM
// 256 threads (4 waves). Tile 192 nodes x 128 outs; wave w: nodes w*48..+47.
// Per source p: issue B-batch0 (8 ld), A prefetch (12 ld), B-batch1 (8 ld)
// BEFORE the barrier closing source p-1; then ds_write both batches, barrier,
// pure-LDS K-loop. B frags consumed hi-phase then lo-phase (32 regs live).
// Register budget ~230 (acc 96 + tmp 64 + Af 48 + B 32 + addr) -> no spills.
__global__ __launch_bounds__(256, 2)
void mfma_gemm(const u16* __restrict__ A1, const u16* __restrict__ A2,
               const uint4* __restrict__ Bf1, const uint4* __restrict__ Bf2,
               const float* __restrict__ bias, u16* __restrict__ out16,
               int do_relu) {
    __shared__ uint4 Bl[4096];  // 64 KB: [ks 0..7][ot 0..7][lane 0..63]
    int tid = threadIdx.x;
    int l = tid & 63;
    int wv = tid >> 6;
    int bn0 = blockIdx.x * 192 + wv * 48;
    int m = l & 15, q = l >> 4;  // q in 0..3

    f4frag acc[3][8];
    #pragma unroll
    for (int i = 0; i < 3; ++i)
        #pragma unroll
        for (int o = 0; o < 8; ++o)
            acc[i][o] = (f4frag){0.f, 0.f, 0.f, 0.f};

    #pragma unroll
    for (int p = 0; p < 2; ++p) {
        const u16* P = p ? A2 : A1;
        const uint4* Bf = p ? Bf2 : Bf1;

        // ---- issue all global loads for this source (pre-barrier) ----
        uint4 t0[8], t1[8];
        #pragma unroll
        for (int u = 0; u < 8; ++u)
            t0[u] = Bf[u * 256 + tid];
        f16frag Af[3][4];
        #pragma unroll
        for (int nt = 0; nt < 3; ++nt)
            #pragma unroll
            for (int s = 0; s < 4; ++s)
                Af[nt][s] = *(const f16frag*)(P + (size_t)(bn0 + nt * 16 + m) * FH + s * 32 + q * 8);
        #pragma unroll
        for (int u = 0; u < 8; ++u)
            t1[u] = Bf[(8 + u) * 256 + tid];

        __syncthreads();   // all waves done reading previous source's Bl

        #pragma unroll
        for (int u = 0; u < 8; ++u)
            Bl[u * 256 + tid] = t0[u];
        #pragma unroll
        for (int u = 0; u < 8; ++u)
            Bl[(8 + u) * 256 + tid] = t1[u];
        __syncthreads();

        #pragma unroll
        for (int s = 0; s < 4; ++s) {
            // ---- hi phase ----
            {
                f16frag B[8];
                #pragma unroll
                for (int ot = 0; ot < 8; ++ot)
                    B[ot] = *(const f16frag*)&Bl[(size_t)(s * 8 + ot) * 64 + l];
                #pragma unroll
                for (int ot = 0; ot < 8; ++ot)
                    #pragma unroll
                    for (int nt = 0; nt < 3; ++nt)
                        acc[nt][ot] = __builtin_amdgcn_mfma_f32_16x16x32_f16(Af[nt][s], B[ot], acc[nt][ot], 0, 0, 0);
            }
            // ---- lo phase ----
            {
                f16frag B[8];
                #pragma unroll
                for (int ot = 0; ot < 8; ++ot)
                    B[ot] = *(const f16frag*)&Bl[(size_t)((s + 4) * 8 + ot) * 64 + l];
                #pragma unroll
                for (int ot = 0; ot < 8; ++ot)
                    #pragma unroll
                    for (int nt = 0; nt < 3; ++nt)
                        acc[nt][ot] = __builtin_amdgcn_mfma_f32_16x16x32_f16(Af[nt][s], B[ot], acc[nt][ot], 0, 0, 0);
            }
        }
    }

    // ---- epilogue: bias (+relu), fp16 store (D: col=l&15, row=q*4+r) ----
    #pragma unroll
    for (int nt = 0; nt < 3; ++nt)
        #pragma unroll
        for (int r = 0; r < 4; ++r) {
            int node = bn0 + nt * 16 + q * 4 + r;
            #pragma unroll
            for (int ot = 0; ot < 8; ++ot) {
                float v = acc[nt][ot][r] + bias[ot * 16 + m];
                if (do_relu) v = fmaxf(v, 0.f);
                __half hv = __float2half(v);
                out16[(size_t)node * FH + ot * 16 + m] = *(u16*)&hv;
            }
        }
}

// --------------------------------------------- fused pooling + final linear
// 256 threads per graph: 16 node-ways x 16 lanes x uint4 (8 fp16 features);
// LDS tree-reduce the 16 partials, then 256-thread GEMV (1 output each).
__global__ __launch_bounds__(256, 2)
void pool_final(const u16* __restrict__ h16, const int* __restrict__ gstart,
                const float* __restrict__ Wlin, const float* __restrict__ blin,
                float* __restrict__ out) {
    __shared__ float smax[16][FH];
    __shared__ float ssum[16][FH];
    __shared__ float pr[2 * FH];
    int g = blockIdx.x;
    int tid = threadIdx.x;
    int way = tid >> 4;           // 0..15
    int lane = tid & 15;          // 0..15
    int f = lane * 8;             // feature base (8 fp16 via uint4)
    int s = gstart[g], e = gstart[g + 1];

    float mx[8], sm[8];
    #pragma unroll
    for (int i = 0; i < 8; ++i) { mx[i] = -INFINITY; sm[i] = 0.f; }
    for (int n = s + way; n < e; n += 16) {
        uint4 u = *(const uint4*)(h16 + (size_t)n * FH + f);
        float2 f0 = __half22float2(*(__half2*)&u.x);
        float2 f1 = __half22float2(*(__half2*)&u.y);
        float2 f2 = __half22float2(*(__half2*)&u.z);
        float2 f3 = __half22float2(*(__half2*)&u.w);
        float v[8] = {f0.x, f0.y, f1.x, f1.y, f2.x, f2.y, f3.x, f3.y};
        #pragma unroll
        for (int i = 0; i < 8; ++i) {
            mx[i] = fmaxf(mx[i], v[i]);
            sm[i] += v[i];
        }
    }
    #pragma unroll
    for (int i = 0; i < 8; ++i) {
        smax[way][f + i] = mx[i];
        ssum[way][f + i] = sm[i];
    }
    __syncthreads();
    int c = e - s;
    if (tid < FH) {
        float m2 = -INFINITY, s2 = 0.f;
        #pragma unroll
        for (int w2 = 0; w2 < 16; ++w2) {
            m2 = fmaxf(m2, smax[w2][tid]);
            s2 += ssum[w2][tid];
        }
        pr[tid] = (c > 0) ? m2 : 0.f;
        pr[FH + tid] = s2 / (float)max(c, 1);
    }
    __syncthreads();
    // GEMV: one output per thread
    int o = tid;
    const float4* wr = (const float4*)(Wlin + (size_t)o * (2 * FH));
    float acc = 0.f;
    #pragma unroll
    for (int j = 0; j < (2 * FH) / 4; ++j) {
        float4 wv = wr[j];
        acc += wv.x * pr[j * 4 + 0] + wv.y * pr[j * 4 + 1] +
               wv.z * pr[j * 4 + 2] + wv.w * pr[j * 4 + 3];
    }
    out[(size_t)g * OUTD + o] = acc + blin[o];
}

extern "C" void kernel_launch(void* const* d_in, const int* in_sizes, int n_in,
                              void* d_out, int out_size, void* d_ws, size_t ws_size,
                              hipStream_t stream) {
    const float* x     = (const float*)d_in[0];
    const int*   ei    = (const int*)d_in[1];
    const int*   batch = (const int*)d_in[2];
    const float* W1l = (const float*)d_in[3];
    const float* b1  = (const float*)d_in[4];
    const float* W1r = (const float*)d_in[5];
    const float* W2l = (const float*)d_in[6];
    const float* b2  = (const float*)d_in[7];
    const float* W2r = (const float*)d_in[8];
    const float* W3l = (const float*)d_in[9];
    const float* b3  = (const float*)d_in[10];
    const float* W3r = (const float*)d_in[11];
    const float* Wlin = (const float*)d_in[12];
    const float* blin = (const float*)d_in[13];
    float* out = (float*)d_out;

    const int E = in_sizes[1] / 2;
    const int N = in_sizes[2];
    const int G = out_size / OUTD;
    const int* src = ei;
    const int* dst = ei + E;
    const int NB = (N + SCHUNK - 1) / SCHUNK;
    const int GB = (N + 191) / 192;   // gemm blocks (192-node tiles)
    const int NP = GB * 192;          // padded node count

    // ---- workspace carve-up ----
    char* w = (char*)d_ws;
    auto alloc = [&](size_t bytes) {
        void* p = (void*)w;
        w += (bytes + 255) & ~(size_t)255;
        return p;
    };
    int*   cnt    = (int*)alloc((size_t)2 * N * sizeof(int));
    int*   cursor = cnt + N;
    int*   rp     = (int*)alloc((size_t)(N + 1) * sizeof(int));
    int*   esrc   = (int*)alloc((size_t)E * sizeof(int));
    int*   gstart = (int*)alloc((size_t)(G + 1) * sizeof(int));
    float* dinv   = (float*)alloc((size_t)N * sizeof(float));
    int*   bsum   = (int*)alloc(64 * sizeof(int));
    int*   boff   = (int*)alloc(64 * sizeof(int));
    u16*   x16    = (u16*)alloc((size_t)NP * FH * sizeof(u16));
    u16*   agg16  = (u16*)alloc((size_t)NP * FH * sizeof(u16));
    u16*   hA16   = (u16*)alloc((size_t)NP * FH * sizeof(u16));
    u16*   hB16   = (u16*)alloc((size_t)NP * FH * sizeof(u16));
    uint4* BF     = (uint4*)alloc((size_t)6 * 4096 * sizeof(uint4));  // 6 x 64KB
    (void)ws_size;

    // ---- prep ----
    prep_x<<<(N * 32 + 255) / 256, 256, 0, stream>>>(x, x16, N * 32);
    prep_w<<<dim3(8, 6), 64, 0, stream>>>(W1l, W1r, W2l, W2r, W3l, W3r, BF);

    // ---- CSR build ----
    hipMemsetAsync(cnt, 0, (size_t)2 * N * sizeof(int), stream);
    hist_kernel<<<(E + 255) / 256, 256, 0, stream>>>(dst, cnt, E);
    scanA_kernel<<<NB, 256, 0, stream>>>(cnt, bsum, N);
    scanB_kernel<<<1, 64, 0, stream>>>(bsum, boff, rp, NB, N);
    scanC_kernel<<<NB, 256, 0, stream>>>(cnt, boff, rp, dinv, N);
    scatter_kernel<<<(E + 255) / 256, 256, 0, stream>>>(src, dst, rp, cursor, esrc, E);
    graph_bounds_kernel<<<(N + 255) / 256, 256, 0, stream>>>(batch, gstart, N, G);

    const int agg_grid = (N + 15) / 16;

    // ---- layer 1 ----
    agg_kernel<<<agg_grid, 256, 0, stream>>>(x16, rp, esrc, dinv, agg16, N);
    mfma_gemm<<<GB, 256, 0, stream>>>(agg16, x16, BF + 0 * 4096, BF + 1 * 4096, b1, hA16, 1);
    // ---- layer 2 ----
    agg_kernel<<<agg_grid, 256, 0, stream>>>(hA16, rp, esrc, dinv, agg16, N);
    mfma_gemm<<<GB, 256, 0, stream>>>(agg16, hA16, BF + 2 * 4096, BF + 3 * 4096, b2, hB16, 1);
    // ---- layer 3 ----
    agg_kernel<<<agg_grid, 256, 0, stream>>>(hB16, rp, esrc, dinv, agg16, N);
    mfma_gemm<<<GB, 256, 0, stream>>>(agg16, hB16, BF + 4 * 4096, BF + 5 * 4096, b3, hA16, 0);

    // ---- fused pool + head ----
    pool_final<<<G, 256, 0, stream>>>(hA16, gstart, Wlin, blin, out);
}

// Round 11
// 334.617 us; speedup vs baseline: 1.1789x; 1.1789x over previous
//
#include <hip/hip_runtime.h>
#include <hip/hip_bf16.h>
#include <hip/hip_fp16.h>

// GraphSAGE 3-layer + pool + linear.
// R11: B staging via __builtin_amdgcn_global_load_lds (async global->LDS,
// zero VGPR round-trip). R10's register-batched staging spilled (VGPR 100,
// WRITE_SIZE 45.9MB vs 12.8MB output = 33MB scratch traffic). Live set now
// acc 96 + Af 48 + B 32 + addr ~190 < 256 cap -> no spills.
// Numerics: fp16 A + exact split-fp16 W (hi+lo), C = A*Whi + A*Wlo.

#define FH 128
#define OUTD 256
#define SCHUNK 2048

typedef unsigned int u32;
typedef unsigned short u16;
typedef __attribute__((ext_vector_type(8))) _Float16 f16frag;
typedef __attribute__((ext_vector_type(4))) float f4frag;

typedef __attribute__((address_space(3))) u32 lds_u32;
typedef __attribute__((address_space(1))) const u32 glb_u32;

__device__ inline void async_copy16(const void* g, void* l) {
    __builtin_amdgcn_global_load_lds((glb_u32*)g, (lds_u32*)l, 16, 0, 0);
}

// ---------------------------------------------------------------- histogram
__global__ void hist_kernel(const int* __restrict__ dst, int* __restrict__ cnt, int E) {
    int e = blockIdx.x * 256 + threadIdx.x;
    if (e < E) atomicAdd(&cnt[dst[e]], 1);
}

// ---------------------------------------------- scan pass A: per-block sums
__global__ void scanA_kernel(const int* __restrict__ cnt, int* __restrict__ bsum, int n) {
    __shared__ int ws[4];
    int b = blockIdx.x, t = threadIdx.x;
    int base = b * SCHUNK + t * 8;
    int s = 0;
    #pragma unroll
    for (int k = 0; k < 8; ++k) {
        int i = base + k;
        s += (i < n) ? cnt[i] : 0;
    }
    #pragma unroll
    for (int off = 32; off >= 1; off >>= 1) s += __shfl_xor(s, off, 64);
    int w = t >> 6, lane = t & 63;
    if (lane == 0) ws[w] = s;
    __syncthreads();
    if (t == 0) bsum[b] = ws[0] + ws[1] + ws[2] + ws[3];
}

// ------------------------------- scan pass B: scan block sums (1 wave)
__global__ void scanB_kernel(const int* __restrict__ bsum, int* __restrict__ boff,
                             int* __restrict__ rp, int B, int n) {
    int t = threadIdx.x;  // 64 threads
    int v = (t < B) ? bsum[t] : 0;
    int x = v;
    #pragma unroll
    for (int off = 1; off < 64; off <<= 1) {
        int y = __shfl_up(x, off, 64);
        if (t >= off) x += y;
    }
    if (t < B) boff[t] = x - v;
    if (t == 63) rp[n] = x;
}

// --------------------------- scan pass C: full exclusive scan + emit rp/dinv
__global__ void scanC_kernel(const int* __restrict__ cnt, const int* __restrict__ boff,
                             int* __restrict__ rp, float* __restrict__ dinv, int n) {
    __shared__ int ws[4];
    int b = blockIdx.x, t = threadIdx.x;
    int base = b * SCHUNK + t * 8;
    int v[8];
    int ts = 0;
    #pragma unroll
    for (int k = 0; k < 8; ++k) {
        int i = base + k;
        v[k] = (i < n) ? cnt[i] : 0;
        ts += v[k];
    }
    int w = t >> 6, lane = t & 63;
    int x = ts;
    #pragma unroll
    for (int off = 1; off < 64; off <<= 1) {
        int y = __shfl_up(x, off, 64);
        if (lane >= off) x += y;
    }
    if (lane == 63) ws[w] = x;
    __syncthreads();
    int woff = 0;
    #pragma unroll
    for (int q = 0; q < 4; ++q) woff += (q < w) ? ws[q] : 0;
    int run = boff[b] + woff + (x - ts);
    #pragma unroll
    for (int k = 0; k < 8; ++k) {
        int i = base + k;
        if (i < n) {
            rp[i] = run;
            dinv[i] = 1.0f / (float)max(v[k], 1);
        }
        run += v[k];
    }
}

// --------------------------------------------------------- CSR edge scatter
__global__ void scatter_kernel(const int* __restrict__ src, const int* __restrict__ dst,
                               const int* __restrict__ rp, int* __restrict__ cursor,
                               int* __restrict__ esrc, int E) {
    int e = blockIdx.x * 256 + threadIdx.x;
    if (e < E) {
        int d = dst[e];
        int pos = rp[d] + atomicAdd(&cursor[d], 1);
        esrc[pos] = src[e];
    }
}

// ------------------------------------------------------- graph range bounds
__global__ void graph_bounds_kernel(const int* __restrict__ batch, int* __restrict__ gstart,
                                    int n, int g) {
    int i = blockIdx.x * 256 + threadIdx.x;
    if (i >= n) return;
    int b = batch[i];
    int pb = (i == 0) ? -1 : batch[i - 1];
    for (int q = pb + 1; q <= b; ++q) gstart[q] = i;
    if (i == n - 1) {
        for (int q = b + 1; q <= g; ++q) gstart[q] = n;
    }
}

// ---------------------------------------------------- prep: x -> fp16 mirror
__global__ void prep_x(const float* __restrict__ x, u16* __restrict__ x16, int n4) {
    int id = blockIdx.x * 256 + threadIdx.x;
    if (id >= n4) return;
    float4 v = *(const float4*)(x + (size_t)id * 4);
    __half h0 = __float2half(v.x), h1 = __float2half(v.y);
    __half h2 = __float2half(v.z), h3 = __float2half(v.w);
    ushort4 s;
    s.x = *(u16*)&h0; s.y = *(u16*)&h1; s.z = *(u16*)&h2; s.w = *(u16*)&h3;
    *(ushort4*)(x16 + (size_t)id * 4) = s;
}

// ------------------- prep: weights -> fp16 hi/lo B fragments (MFMA order)
// Per array: Bf[(ks*8 + ot)*64 + lane], lane l holds
// W[out=ot*16+(l&15)][k = (ks&3)*32 + (l>>4)*8 + i], i=0..7.
// ks 0-3: hi = f16(W); ks 4-7: lo = f16(W - hi).
__global__ void prep_w(const float* __restrict__ W0, const float* __restrict__ W1,
                       const float* __restrict__ W2, const float* __restrict__ W3,
                       const float* __restrict__ W4, const float* __restrict__ W5,
                       uint4* __restrict__ Bf) {
    const float* Ws[6] = {W0, W1, W2, W3, W4, W5};
    int ks = blockIdx.x;      // 0..7
    int arr = blockIdx.y;     // 0..5
    int l = threadIdx.x;      // 0..63
    const float* W = Ws[arr];
    bool use_lo = (ks >= 4);
    int kb = (ks & 3) * 32 + (l >> 4) * 8;
    uint4* out = Bf + (size_t)arr * 4096;
    #pragma unroll
    for (int ot = 0; ot < 8; ++ot) {
        int o = ot * 16 + (l & 15);
        u32 h[8];
        #pragma unroll
        for (int i = 0; i < 8; ++i) {
            float v = W[o * 128 + kb + i];
            __half hi = __float2half(v);
            if (use_lo) {
                float rem = v - __half2float(hi);
                __half lo = __float2half(rem);
                h[i] = *(u16*)&lo;
            } else {
                h[i] = *(u16*)&hi;
            }
        }
        uint4 u;
        u.x = h[0] | (h[1] << 16);
        u.y = h[2] | (h[3] << 16);
        u.z = h[4] | (h[5] << 16);
        u.w = h[6] | (h[7] << 16);
        out[(ks * 8 + ot) * 64 + l] = u;
    }
}

// --------------------------------------------------- mean aggregation (CSR)
// 16 lanes per node; lane covers 8 fp16 features (uint4 = 16B); x8 edge unroll
// -> 8 independent 256B gathers in flight per node group.
__device__ inline void add8(float* a, uint4 u) {
    float2 f0 = __half22float2(*(__half2*)&u.x);
    float2 f1 = __half22float2(*(__half2*)&u.y);
    float2 f2 = __half22float2(*(__half2*)&u.z);
    float2 f3 = __half22float2(*(__half2*)&u.w);
    a[0] += f0.x; a[1] += f0.y; a[2] += f1.x; a[3] += f1.y;
    a[4] += f2.x; a[5] += f2.y; a[6] += f3.x; a[7] += f3.y;
}

__global__ void agg_kernel(const u16* __restrict__ h16,
                           const int* __restrict__ rp, const int* __restrict__ esrc,
                           const float* __restrict__ dinv,
                           u16* __restrict__ agg16, int n_nodes) {
    int node = blockIdx.x * 16 + (threadIdx.x >> 4);
    if (node >= n_nodes) return;
    int lane = threadIdx.x & 15;
    int f = lane * 8;
    int s0 = rp[node], s1 = rp[node + 1];
    float a0[8] = {0, 0, 0, 0, 0, 0, 0, 0};
    float a1[8] = {0, 0, 0, 0, 0, 0, 0, 0};
    float a2[8] = {0, 0, 0, 0, 0, 0, 0, 0};
    float a3[8] = {0, 0, 0, 0, 0, 0, 0, 0};
    int j = s0;
    for (; j + 8 <= s1; j += 8) {
        int i0 = esrc[j],     i1 = esrc[j + 1], i2 = esrc[j + 2], i3 = esrc[j + 3];
        int i4 = esrc[j + 4], i5 = esrc[j + 5], i6 = esrc[j + 6], i7 = esrc[j + 7];
        uint4 u0 = *(const uint4*)(h16 + (size_t)i0 * FH + f);
        uint4 u1 = *(const uint4*)(h16 + (size_t)i1 * FH + f);
        uint4 u2 = *(const uint4*)(h16 + (size_t)i2 * FH + f);
        uint4 u3 = *(const uint4*)(h16 + (size_t)i3 * FH + f);
        uint4 u4 = *(const uint4*)(h16 + (size_t)i4 * FH + f);
        uint4 u5 = *(const uint4*)(h16 + (size_t)i5 * FH + f);
        uint4 u6 = *(const uint4*)(h16 + (size_t)i6 * FH + f);
        uint4 u7 = *(const uint4*)(h16 + (size_t)i7 * FH + f);
        add8(a0, u0); add8(a1, u1); add8(a2, u2); add8(a3, u3);
        add8(a0, u4); add8(a1, u5); add8(a2, u6); add8(a3, u7);
    }
    if (j + 4 <= s1) {
        int i0 = esrc[j], i1 = esrc[j + 1], i2 = esrc[j + 2], i3 = esrc[j + 3];
        uint4 u0 = *(const uint4*)(h16 + (size_t)i0 * FH + f);
        uint4 u1 = *(const uint4*)(h16 + (size_t)i1 * FH + f);
        uint4 u2 = *(const uint4*)(h16 + (size_t)i2 * FH + f);
        uint4 u3 = *(const uint4*)(h16 + (size_t)i3 * FH + f);
        add8(a0, u0); add8(a1, u1); add8(a2, u2); add8(a3, u3);
        j += 4;
    }
    for (; j < s1; ++j) {
        uint4 u0 = *(const uint4*)(h16 + (size_t)esrc[j] * FH + f);
        add8(a0, u0);
    }
    float di = dinv[node];
    u32 oh[8];
    #pragma unroll
    for (int i = 0; i < 8; ++i) {
        __half hv = __float2half((a0[i] + a1[i] + a2[i] + a3[i]) * di);
        oh[i] = *(u16*)&hv;
    }
    uint4 w;
    w.x = oh[0] | (oh[1] << 16);
    w.y = oh[2] | (oh[3] << 16);
    w.z = oh[4] | (oh[5] << 16);
    w.w = oh[6] | (oh[7] << 16);
    *(uint4*)(agg16 + (size_t)node * FH + f) = w;
}

// ----------------------------------------------------------- MFMA SAGE GEMM
// 256 threads (4 waves). Tile 192 nodes x 128 outs; wave w: nodes w*48..+47.
// Per source p: A prefetch to regs (12 loads, issued pre-barrier; the
// barrier's vmcnt(0) drains them), barrier, 16x global_load_lds width=16
// (async B staging, no VGPRs), barrier, pure-LDS K-loop (hi then lo phase).
__global__ __launch_bounds__(256, 2)
void mfma_gemm(const u16* __restrict__ A1, const u16* __restrict__ A2,
               const uint4* __restrict__ Bf1, const uint4* __restrict__ Bf2,
               const float* __restrict__ bias, u16* __restrict__ out16,
               int do_relu) {
    __shared__ uint4 Bl[4096];  // 64 KB: [ks 0..7][ot 0..7][lane 0..63]
    int tid = threadIdx.x;
    int l = tid & 63;
    int wv = tid >> 6;
    int bn0 = blockIdx.x * 192 + wv * 48;
    int m = l & 15, q = l >> 4;  // q in 0..3

    f4frag acc[3][8];
    #pragma unroll
    for (int i = 0; i < 3; ++i)
        #pragma unroll
        for (int o = 0; o < 8; ++o)
            acc[i][o] = (f4frag){0.f, 0.f, 0.f, 0.f};

    #pragma unroll
    for (int p = 0; p < 2; ++p) {
        const u16* P = p ? A2 : A1;
        const uint4* Bf = p ? Bf2 : Bf1;

        // ---- A prefetch (registers only; in flight across the barrier) ----
        f16frag Af[3][4];
        #pragma unroll
        for (int nt = 0; nt < 3; ++nt)
            #pragma unroll
            for (int s = 0; s < 4; ++s)
                Af[nt][s] = *(const f16frag*)(P + (size_t)(bn0 + nt * 16 + m) * FH + s * 32 + q * 8);

        __syncthreads();   // all waves done reading previous source's Bl

        // ---- async B staging: 16 x (1 KB/wave) direct global->LDS ----
        #pragma unroll
        for (int u = 0; u < 16; ++u)
            async_copy16(Bf + (size_t)u * 256 + wv * 64 + l,
                         &Bl[u * 256 + wv * 64]);
        __syncthreads();   // drains vmcnt -> staging complete

        #pragma unroll
        for (int s = 0; s < 4; ++s) {
            // ---- hi phase ----
            {
                f16frag B[8];
                #pragma unroll
                for (int ot = 0; ot < 8; ++ot)
                    B[ot] = *(const f16frag*)&Bl[(size_t)(s * 8 + ot) * 64 + l];
                #pragma unroll
                for (int ot = 0; ot < 8; ++ot)
                    #pragma unroll
                    for (int nt = 0; nt < 3; ++nt)
                        acc[nt][ot] = __builtin_amdgcn_mfma_f32_16x16x32_f16(Af[nt][s], B[ot], acc[nt][ot], 0, 0, 0);
            }
            // ---- lo phase ----
            {
                f16frag B[8];
                #pragma unroll
                for (int ot = 0; ot < 8; ++ot)
                    B[ot] = *(const f16frag*)&Bl[(size_t)((s + 4) * 8 + ot) * 64 + l];
                #pragma unroll
                for (int ot = 0; ot < 8; ++ot)
                    #pragma unroll
                    for (int nt = 0; nt < 3; ++nt)
                        acc[nt][ot] = __builtin_amdgcn_mfma_f32_16x16x32_f16(Af[nt][s], B[ot], acc[nt][ot], 0, 0, 0);
            }
        }
    }

    // ---- epilogue: bias (+relu), fp16 store (D: col=l&15, row=q*4+r) ----
    #pragma unroll
    for (int nt = 0; nt < 3; ++nt)
        #pragma unroll
        for (int r = 0; r < 4; ++r) {
            int node = bn0 + nt * 16 + q * 4 + r;
            #pragma unroll
            for (int ot = 0; ot < 8; ++ot) {
                float v = acc[nt][ot][r] + bias[ot * 16 + m];
                if (do_relu) v = fmaxf(v, 0.f);
                __half hv = __float2half(v);
                out16[(size_t)node * FH + ot * 16 + m] = *(u16*)&hv;
            }
        }
}

// --------------------------------------------- fused pooling + final linear
// 256 threads per graph: 16 node-ways x 16 lanes x uint4 (8 fp16 features);
// LDS tree-reduce the 16 partials, then 256-thread GEMV (1 output each).
__global__ __launch_bounds__(256, 2)
void pool_final(const u16* __restrict__ h16, const int* __restrict__ gstart,
                const float* __restrict__ Wlin, const float* __restrict__ blin,
                float* __restrict__ out) {
    __shared__ float smax[16][FH];
    __shared__ float ssum[16][FH];
    __shared__ float pr[2 * FH];
    int g = blockIdx.x;
    int tid = threadIdx.x;
    int way = tid >> 4;           // 0..15
    int lane = tid & 15;          // 0..15
    int f = lane * 8;             // feature base (8 fp16 via uint4)
    int s = gstart[g], e = gstart[g + 1];

    float mx[8], sm[8];
    #pragma unroll
    for (int i = 0; i < 8; ++i) { mx[i] = -INFINITY; sm[i] = 0.f; }
    for (int n = s + way; n < e; n += 16) {
        uint4 u = *(const uint4*)(h16 + (size_t)n * FH + f);
        float2 f0 = __half22float2(*(__half2*)&u.x);
        float2 f1 = __half22float2(*(__half2*)&u.y);
        float2 f2 = __half22float2(*(__half2*)&u.z);
        float2 f3 = __half22float2(*(__half2*)&u.w);
        float v[8] = {f0.x, f0.y, f1.x, f1.y, f2.x, f2.y, f3.x, f3.y};
        #pragma unroll
        for (int i = 0; i < 8; ++i) {
            mx[i] = fmaxf(mx[i], v[i]);
            sm[i] += v[i];
        }
    }
    #pragma unroll
    for (int i = 0; i < 8; ++i) {
        smax[way][f + i] = mx[i];
        ssum[way][f + i] = sm[i];
    }
    __syncthreads();
    int c = e - s;
    if (tid < FH) {
        float m2 = -INFINITY, s2 = 0.f;
        #pragma unroll
        for (int w2 = 0; w2 < 16; ++w2) {
            m2 = fmaxf(m2, smax[w2][tid]);
            s2 += ssum[w2][tid];
        }
        pr[tid] = (c > 0) ? m2 : 0.f;
        pr[FH + tid] = s2 / (float)max(c, 1);
    }
    __syncthreads();
    // GEMV: one output per thread
    int o = tid;
    const float4* wr = (const float4*)(Wlin + (size_t)o * (2 * FH));
    float acc = 0.f;
    #pragma unroll
    for (int j = 0; j < (2 * FH) / 4; ++j) {
        float4 wv = wr[j];
        acc += wv.x * pr[j * 4 + 0] + wv.y * pr[j * 4 + 1] +
               wv.z * pr[j * 4 + 2] + wv.w * pr[j * 4 + 3];
    }
    out[(size_t)g * OUTD + o] = acc + blin[o];
}

extern "C" void kernel_launch(void* const* d_in, const int* in_sizes, int n_in,
                              void* d_out, int out_size, void* d_ws, size_t ws_size,
                              hipStream_t stream) {
    const float* x     = (const float*)d_in[0];
    const int*   ei    = (const int*)d_in[1];
    const int*   batch = (const int*)d_in[2];
    const float* W1l = (const float*)d_in[3];
    const float* b1  = (const float*)d_in[4];
    const float* W1r = (const float*)d_in[5];
    const float* W2l = (const float*)d_in[6];
    const float* b2  = (const float*)d_in[7];
    const float* W2r = (const float*)d_in[8];
    const float* W3l = (const float*)d_in[9];
    const float* b3  = (const float*)d_in[10];
    const float* W3r = (const float*)d_in[11];
    const float* Wlin = (const float*)d_in[12];
    const float* blin = (const float*)d_in[13];
    float* out = (float*)d_out;

    const int E = in_sizes[1] / 2;
    const int N = in_sizes[2];
    const int G = out_size / OUTD;
    const int* src = ei;
    const int* dst = ei + E;
    const int NB = (N + SCHUNK - 1) / SCHUNK;
    const int GB = (N + 191) / 192;   // gemm blocks (192-node tiles)
    const int NP = GB * 192;          // padded node count

    // ---- workspace carve-up ----
    char* w = (char*)d_ws;
    auto alloc = [&](size_t bytes) {
        void* p = (void*)w;
        w += (bytes + 255) & ~(size_t)255;
        return p;
    };
    int*   cnt    = (int*)alloc((size_t)2 * N * sizeof(int));
    int*   cursor = cnt + N;
    int*   rp     = (int*)alloc((size_t)(N + 1) * sizeof(int));
    int*   esrc   = (int*)alloc((size_t)E * sizeof(int));
    int*   gstart = (int*)alloc((size_t)(G + 1) * sizeof(int));
    float* dinv   = (float*)alloc((size_t)N * sizeof(float));
    int*   bsum   = (int*)alloc(64 * sizeof(int));
    int*   boff   = (int*)alloc(64 * sizeof(int));
    u16*   x16    = (u16*)alloc((size_t)NP * FH * sizeof(u16));
    u16*   agg16  = (u16*)alloc((size_t)NP * FH * sizeof(u16));
    u16*   hA16   = (u16*)alloc((size_t)NP * FH * sizeof(u16));
    u16*   hB16   = (u16*)alloc((size_t)NP * FH * sizeof(u16));
    uint4* BF     = (uint4*)alloc((size_t)6 * 4096 * sizeof(uint4));  // 6 x 64KB
    (void)ws_size;

    // ---- prep ----
    prep_x<<<(N * 32 + 255) / 256, 256, 0, stream>>>(x, x16, N * 32);
    prep_w<<<dim3(8, 6), 64, 0, stream>>>(W1l, W1r, W2l, W2r, W3l, W3r, BF);

    // ---- CSR build ----
    hipMemsetAsync(cnt, 0, (size_t)2 * N * sizeof(int), stream);
    hist_kernel<<<(E + 255) / 256, 256, 0, stream>>>(dst, cnt, E);
    scanA_kernel<<<NB, 256, 0, stream>>>(cnt, bsum, N);
    scanB_kernel<<<1, 64, 0, stream>>>(bsum, boff, rp, NB, N);
    scanC_kernel<<<NB, 256, 0, stream>>>(cnt, boff, rp, dinv, N);
    scatter_kernel<<<(E + 255) / 256, 256, 0, stream>>>(src, dst, rp, cursor, esrc, E);
    graph_bounds_kernel<<<(N + 255) / 256, 256, 0, stream>>>(batch, gstart, N, G);

    const int agg_grid = (N + 15) / 16;

    // ---- layer 1 ----
    agg_kernel<<<agg_grid, 256, 0, stream>>>(x16, rp, esrc, dinv, agg16, N);
    mfma_gemm<<<GB, 256, 0, stream>>>(agg16, x16, BF + 0 * 4096, BF + 1 * 4096, b1, hA16, 1);
    // ---- layer 2 ----
    agg_kernel<<<agg_grid, 256, 0, stream>>>(hA16, rp, esrc, dinv, agg16, N);
    mfma_gemm<<<GB, 256, 0, stream>>>(agg16, hA16, BF + 2 * 4096, BF + 3 * 4096, b2, hB16, 1);
    // ---- layer 3 ----
    agg_kernel<<<agg_grid, 256, 0, stream>>>(hB16, rp, esrc, dinv, agg16, N);
    mfma_gemm<<<GB, 256, 0, stream>>>(agg16, hB16, BF + 4 * 4096, BF + 5 * 4096, b3, hA16, 0);

    // ---- fused pool + head ----
    pool_final<<<G, 256, 0, stream>>>(hA16, gstart, Wlin, blin, out);
}